// Round 7
// baseline (709.263 us; speedup 1.0000x reference)
//
#include <hip/hip_runtime.h>

// B=2, T=12, C=128, H=W=32, heads=4, dh=32, layers=5. fp32 I/O.
// Algebra: key-axis softmax cancels q-conv & att_b; attention weights are
// query-independent (head output broadcast over the 12 frames).
// Layout: channels-last fp32 activations [img][1024px][128c] + padded bf16
// copies A2[img][34*34 pos][128c] so conv MFMA A-fragments are direct
// contiguous global loads (no LDS in the convs).
// R7: conv tile 64px x 64co (grid 768 = 3 blocks/CU -> 3 waves/SIMD) +
// 4-deep prefetch rotation to cover ~200cy L2 latency.
#define NELEM 3145728
#define IMG 24
#define CH 128
#define HW 1024
#define PADP 1156          // 34*34
#define A2IMG 147968       // 1156*128

using short8  = __attribute__((ext_vector_type(8))) short;
using float4v = __attribute__((ext_vector_type(4))) float;

__device__ inline unsigned short f2bf(float f){
    union { float f; unsigned u; } c; c.f = f;
    return (unsigned short)((c.u + 0x7FFF + ((c.u >> 16) & 1)) >> 16);
}
__device__ inline float bf2f(unsigned short h){
    union { unsigned u; float f; } c; c.u = ((unsigned)h) << 16; return c.f;
}

// ---------------- weight transforms (fp32 -> bf16 MFMA-B layout) ----------------
__global__ void k_w2dense(const float* __restrict__ w1, const float* __restrict__ w2src,
                          unsigned short* __restrict__ dst){
    int idx = blockIdx.x * 256 + threadIdx.x;           // 10*147456
    if (idx >= 1474560) return;
    int li2 = idx / 147456, r1 = idx - li2 * 147456;
    int j = r1 & 7, t16 = r1 >> 3;
    int co = t16 & 127, tcq = t16 >> 7;
    int quad = tcq & 3, cc = (tcq >> 2) & 3, tap = tcq >> 4;
    const float* base = ((li2 & 1) ? w2src : w1) + (size_t)(li2 >> 1) * 147456;
    dst[idx] = f2bf(base[(co * 128 + cc * 32 + quad * 8 + j) * 9 + tap]);
}
__global__ void k_w2kv(const float* __restrict__ w, unsigned short* __restrict__ dst){
    int idx = blockIdx.x * 256 + threadIdx.x;           // 5*36864
    if (idx >= 184320) return;
    int li = idx / 36864, r1 = idx - li * 36864;
    int j = r1 & 7, t16 = r1 >> 3;
    int co = t16 & 127, tq = t16 >> 7;
    int quad = tq & 3, tap = tq >> 2;
    int h = co >> 5, col = co & 31;
    dst[idx] = f2bf(w[(size_t)(((li * 4 + h) * 32 + col) * 32 + quad * 8 + j) * 9 + tap]);
}

// ---------------- zero the padded borders of the A2 buffers ----------------
__global__ void k_border(unsigned short* __restrict__ a, unsigned short* __restrict__ b){
    int gid = blockIdx.x * 256 + threadIdx.x;   // 2*24*132*128 = 811008
    if (gid >= 811008) return;
    int c = gid & 127, r = gid >> 7;
    int bp = r % 132, r2 = r / 132;
    int img = r2 % 24, buf = r2 / 24;
    int pos;
    if (bp < 34) pos = bp;
    else if (bp < 68) pos = 33 * 34 + (bp - 34);
    else if (bp < 100) pos = (bp - 68 + 1) * 34;
    else pos = (bp - 100 + 1) * 34 + 33;
    unsigned short* p = buf ? b : a;
    p[(size_t)img * A2IMG + pos * 128 + c] = 0;
}

// ---------------- init: NCHW fp32 input -> CL cur fp32 + A2a bf16 ----------------
__global__ __launch_bounds__(256) void k_init(const float* __restrict__ in,
    float* __restrict__ cur, unsigned short* __restrict__ a2){
    int gid = blockIdx.x * 256 + threadIdx.x;   // 24*1024*32
    int c4 = (gid & 31) * 4, px = (gid >> 5) & 1023, img = gid >> 15;
    float4v v;
    #pragma unroll
    for (int j = 0; j < 4; j++)
        v[j] = in[((size_t)img * 128 + c4 + j) * HW + px];
    *(float4v*)(cur + ((size_t)img * HW + px) * 128 + c4) = v;
    int pos = ((px >> 5) + 1) * 34 + (px & 31) + 1;
    unsigned short* ap = a2 + ((size_t)img * PADP + pos) * 128 + c4;
    #pragma unroll
    for (int j = 0; j < 4; j++) ap[j] = f2bf(v[j]);
}

// ---------------- implicit-GEMM 3x3 conv, channels-last, no LDS ----------------
// grid (16 rq, 24 img, 2 zc) = 768 blocks (3/CU). Block 256 = 4 waves (wm x wn).
// Block tile 64px(2 rows) x 64co. Wave: row y0+wm, 2 m-frags x 2 n-frags.
// A: direct global short8 from padded A2 (tap shift = address offset).
// B: global short8 from frag-native W2 (L2-resident).
// Both rotated through a 4-deep prefetch pipeline.
template<bool GROUPED, bool RELU, bool RES, bool EF32, bool EA2, bool STAT>
__global__ __launch_bounds__(256, 3) void k_conv(
    const unsigned short* __restrict__ a2in, const unsigned short* __restrict__ w2,
    const float* __restrict__ bias, const float* __restrict__ res,
    float* __restrict__ outf, unsigned short* __restrict__ outa2,
    float* __restrict__ pstat)
{
    const int y0 = blockIdx.x * 2;
    const int img = blockIdx.y;
    const int zc = blockIdx.z;
    const int t = threadIdx.x;
    const int wave = t >> 6, lane = t & 63;
    const int wm = wave & 1, wn = wave >> 1;
    const int n16 = lane & 15, quad = lane >> 4;
    const int cog = zc * 64 + wn * 32;          // wave's co base
    const int head = zc * 2 + wn;               // co group (grouped head / GN group)
    const int y = y0 + wm;                      // wave's image row

    const short8* w8 = reinterpret_cast<const short8*>(w2);
    const unsigned short* abase = a2in + (size_t)img * A2IMG;

    constexpr int NK = GROUPED ? 9 : 36;
    constexpr int D = 4;                        // prefetch depth

    float4v acc[2][2];
    #pragma unroll
    for (int a = 0; a < 2; a++)
        #pragma unroll
        for (int b = 0; b < 2; b++) acc[a][b] = (float4v){0.f,0.f,0.f,0.f};

    short8 af[D][2], bf[D][2];

    auto loadA = [&](int k, int s){
        const int tap = GROUPED ? k : (k >> 2);
        const int cc  = GROUPED ? 0 : (k & 3);
        const int ky = tap / 3, kx = tap - ky * 3;
        const int ci = (GROUPED ? head * 32 : cc * 32) + quad * 8;
        #pragma unroll
        for (int mt = 0; mt < 2; mt++) {
            int pos = (y + ky) * 34 + mt * 16 + kx + n16;
            af[s][mt] = *reinterpret_cast<const short8*>(abase + (size_t)pos * 128 + ci);
        }
    };
    auto loadB = [&](int k, int s){
        #pragma unroll
        for (int nt = 0; nt < 2; nt++)
            bf[s][nt] = w8[(k * 4 + quad) * 128 + cog + nt * 16 + n16];
    };

    #pragma unroll
    for (int k = 0; k < D; k++) { loadA(k, k); loadB(k, k); }
    #pragma unroll
    for (int k = 0; k < NK; k++) {
        const int s = k % D;
        #pragma unroll
        for (int mt = 0; mt < 2; mt++)
            #pragma unroll
            for (int nt = 0; nt < 2; nt++)
                acc[mt][nt] = __builtin_amdgcn_mfma_f32_16x16x32_bf16(
                    af[s][mt], bf[s][nt], acc[mt][nt], 0, 0, 0);
        if (k + D < NK) { loadA(k + D, s); loadB(k + D, s); }
    }

    // epilogue: D col = n16 (co offset), row = quad*4+reg (x offset)
    float s1 = 0.f, s2 = 0.f;
    #pragma unroll
    for (int mt = 0; mt < 2; mt++) {
        int xb = mt * 16 + quad * 4;
        #pragma unroll
        for (int nt = 0; nt < 2; nt++) {
            int co = cog + nt * 16 + n16;
            float bb = bias[co];
            #pragma unroll
            for (int r = 0; r < 4; r++) {
                int px = y * 32 + xb + r;
                float val = acc[mt][nt][r] + bb;
                if (RELU) val = fmaxf(val, 0.f);
                size_t ci = ((size_t)img * HW + px) * 128 + co;
                if (RES) val += res[ci];
                if (EF32) outf[ci] = val;
                if (EA2) {
                    int pos = (y + 1) * 34 + xb + r + 1;
                    outa2[((size_t)img * PADP + pos) * 128 + co] = f2bf(val);
                }
                if (STAT) { s1 += val; s2 += val * val; }
            }
        }
    }
    if (STAT) {
        #pragma unroll
        for (int o = 32; o > 0; o >>= 1) {
            s1 += __shfl_down(s1, o); s2 += __shfl_down(s2, o);
        }
        if (lane == 0) {
            atomicAdd(&pstat[(img * 4 + head) * 2], s1);
            atomicAdd(&pstat[(img * 4 + head) * 2 + 1], s2);
        }
    }
}

// ---------------- attention logit conv (reads padded bf16 A2v) ----------------
__global__ __launch_bounds__(256) void k_attn(
    const unsigned short* __restrict__ a2v, const float* __restrict__ aw,
    float* __restrict__ ak, float* __restrict__ pstat)
{
    const int img = blockIdx.x;            // b*12 + l
    const int h = blockIdx.y;
    const int y0 = blockIdx.z * 8;
    const int t = threadIdx.x;
    const int b = img / 12, l = img - b * 12;

    if (blockIdx.x == 0 && blockIdx.y == 0 && blockIdx.z == 0 && t < 192)
        pstat[t] = 0.f;                     // zero GN stats for this layer's ff2

    __shared__ float sxv[32 * 341];         // ci-major, pos stride 341
    __shared__ float spos[32];
    if (t < 32) {
        int j2 = t & ~1;
        float freq = __expf(-(float)j2 * 0.28782313662425576f);
        float ang = (float)l * freq;
        spos[t] = (t & 1) ? __cosf(ang) : __sinf(ang);
    }
    __syncthreads();

    // stage 10 padded rows x 34 cols x 32 ci, add pos on interior
    const unsigned short* vb = a2v + (size_t)img * A2IMG + h * 32;
    for (int idx = t; idx < 1360; idx += 256) {
        int q = idx & 3, pos = idx >> 2;
        int ppos = y0 * 34 + pos;
        int row = y0 + pos / 34, col = pos - (pos / 34) * 34;
        bool inter = (row >= 1 && row <= 32 && col >= 1 && col <= 32);
        short8 vv = *reinterpret_cast<const short8*>(vb + (size_t)ppos * 128 + q * 8);
        #pragma unroll
        for (int j = 0; j < 8; j++) {
            float f = bf2f((unsigned short)vv[j]);
            if (inter) f += spos[q * 8 + j];
            sxv[(q * 8 + j) * 341 + pos] = f;
        }
    }
    __syncthreads();

    const float* wb = aw + (h * 64 + 32) * 9;   // K-half weights (uniform -> s_load)
    const int r = t >> 5, xx = t & 31;
    float acc = 0.f;
    #pragma unroll 4
    for (int ci = 0; ci < 32; ci++) {
        #pragma unroll
        for (int ky = 0; ky < 3; ky++)
            #pragma unroll
            for (int kx = 0; kx < 3; kx++)
                acc = fmaf(sxv[ci * 341 + (r + ky) * 34 + xx + kx],
                           wb[ci * 9 + ky * 3 + kx], acc);
    }
    ak[((b * 4 + h) * 12 + l) * HW + (y0 + r) * 32 + xx] = acc;
}

// ---------------- fused softmax + weighted sum + residual (+A2a emit) ----------------
__global__ __launch_bounds__(256) void k_wsum(const float* __restrict__ ak,
    const float* __restrict__ v, float* __restrict__ cur,
    unsigned short* __restrict__ a2a)
{
    int gid = blockIdx.x * 256 + threadIdx.x;   // 2*1024*32
    int c4 = (gid & 31) * 4, px = (gid >> 5) & 1023, b = gid >> 15;
    int h = c4 >> 5;
    const float* wp = ak + ((b * 4 + h) * 12) * HW + px;
    float a[12], m = -1e30f;
    #pragma unroll
    for (int l = 0; l < 12; l++) { a[l] = wp[l * HW]; m = fmaxf(m, a[l]); }
    float ssum = 0.f;
    #pragma unroll
    for (int l = 0; l < 12; l++) { a[l] = __expf(a[l] - m); ssum += a[l]; }
    float invs = 1.f / ssum;
    float4v s = (float4v){0.f,0.f,0.f,0.f};
    #pragma unroll
    for (int l = 0; l < 12; l++) {
        float4v vv = *(const float4v*)(v + (((size_t)(b * 12 + l) * HW) + px) * 128 + c4);
        #pragma unroll
        for (int j = 0; j < 4; j++) s[j] += a[l] * vv[j];
    }
    #pragma unroll
    for (int j = 0; j < 4; j++) s[j] *= invs;
    int pos = ((px >> 5) + 1) * 34 + (px & 31) + 1;
    #pragma unroll
    for (int l = 0; l < 12; l++) {
        size_t ci = (((size_t)(b * 12 + l) * HW) + px) * 128 + c4;
        float4v cv = *(float4v*)(cur + ci);
        #pragma unroll
        for (int j = 0; j < 4; j++) cv[j] += s[j];
        *(float4v*)(cur + ci) = cv;
        unsigned short* ap = a2a + ((size_t)(b * 12 + l) * PADP + pos) * 128 + c4;
        #pragma unroll
        for (int j = 0; j < 4; j++) ap[j] = f2bf(cv[j]);
    }
}

// ---------------- GroupNorm finalize+apply (in-place on cur / final NCHW) ----------------
template<bool LAST>
__global__ __launch_bounds__(256) void k_gnapply(const float* __restrict__ y,
    const float* __restrict__ pstat, const float* __restrict__ gw,
    const float* __restrict__ gb, float* __restrict__ cur,
    unsigned short* __restrict__ a2a, float* __restrict__ outp)
{
    int gid = blockIdx.x * 256 + threadIdx.x;   // 24*1024*32
    if (!LAST) {
        int c4 = (gid & 31) * 4, px = (gid >> 5) & 1023, img = gid >> 15;
        int g = c4 >> 5;
        float S = pstat[(img * 4 + g) * 2], Q = pstat[(img * 4 + g) * 2 + 1];
        float mu = S * (1.f / 32768.f);
        float inv = rsqrtf(Q * (1.f / 32768.f) - mu * mu + 1e-5f);
        float4v vv = *(const float4v*)(y + ((size_t)img * HW + px) * 128 + c4);
        int pos = ((px >> 5) + 1) * 34 + (px & 31) + 1;
        size_t ci = ((size_t)img * HW + px) * 128 + c4;
        unsigned short* ap = a2a + ((size_t)img * PADP + pos) * 128 + c4;
        #pragma unroll
        for (int j = 0; j < 4; j++) {
            float val = (vv[j] - mu) * inv * gw[c4 + j] + gb[c4 + j];
            vv[j] = val;
            ap[j] = f2bf(val);
        }
        *(float4v*)(cur + ci) = vv;
    } else {
        int px4 = (gid & 255) * 4, c = (gid >> 8) & 127, img = gid >> 15;
        int g = c >> 5;
        float S = pstat[(img * 4 + g) * 2], Q = pstat[(img * 4 + g) * 2 + 1];
        float mu = S * (1.f / 32768.f);
        float inv = rsqrtf(Q * (1.f / 32768.f) - mu * mu + 1e-5f);
        float gg = gw[c], bb = gb[c];
        float4v o;
        #pragma unroll
        for (int j = 0; j < 4; j++) {
            float val = y[((size_t)img * HW + px4 + j) * 128 + c];
            o[j] = (val - mu) * inv * gg + bb;
        }
        *(float4v*)(outp + ((size_t)img * 128 + c) * HW + px4) = o;
    }
}

extern "C" void kernel_launch(void* const* d_in, const int* in_sizes, int n_in,
                              void* d_out, int out_size, void* d_ws, size_t ws_size,
                              hipStream_t stream)
{
    const float* input = (const float*)d_in[0];
    // d_in[1] q_w, d_in[2] q_b, d_in[6] att_b cancel in key-axis softmax.
    const float* kv_w  = (const float*)d_in[3];
    const float* kv_b  = (const float*)d_in[4];
    const float* att_w = (const float*)d_in[5];
    const float* ff1_w = (const float*)d_in[7];
    const float* ff1_b = (const float*)d_in[8];
    const float* ff2_w = (const float*)d_in[9];
    const float* ff2_b = (const float*)d_in[10];
    const float* gn_w  = (const float*)d_in[11];
    const float* gn_b  = (const float*)d_in[12];

    // ws layout (~30.5 MB): no buffer aliases another live buffer.
    float* ws  = (float*)d_ws;
    float* cur = ws;                          // CL fp32 (24,1024,128)
    float* ak  = ws + (size_t)NELEM;          // 98304
    float* pstat = ak + 98304;                // 192
    unsigned short* W2d  = (unsigned short*)(pstat + 192);   // 1,474,560
    unsigned short* W2kv = W2d + 1474560;                    // 184,320
    unsigned short* A2v  = W2kv + 184320;                    // 24*147968
    unsigned short* A2a  = A2v + (size_t)IMG * A2IMG;        // 24*147968
    // d_out doubles as the fp32 v buffer (dead before the final output write).
    float* v    = (float*)d_out;
    float* outp = (float*)d_out;

    k_w2dense<<<5760, 256, 0, stream>>>(ff1_w, ff2_w, W2d);
    k_w2kv<<<720, 256, 0, stream>>>(kv_w, W2kv);
    k_border<<<3168, 256, 0, stream>>>(A2a, A2v);
    k_init<<<3072, 256, 0, stream>>>(input, cur, A2a);

    for (int li = 0; li < 5; li++) {
        // v (d_out) = grouped conv(A2a) + kv_b ; also emit A2v bf16
        k_conv<true, false, false, true, true, false><<<dim3(16, IMG, 2), 256, 0, stream>>>(
            A2a, W2kv + (size_t)li * 36864, kv_b + li * 128, nullptr, v, A2v, nullptr);
        // attention logits from k = v + pos (also zeroes pstat for this layer)
        k_attn<<<dim3(IMG, 4, 4), 256, 0, stream>>>(A2v, att_w + (size_t)li * 2304, ak, pstat);
        // cur += softmax-weighted sum of v (broadcast over frames); emit A2a
        k_wsum<<<256, 256, 0, stream>>>(ak, v, cur, A2a);
        // f1 = relu(conv(A2a, ff1)) -> A2v only
        k_conv<false, true, false, false, true, false><<<dim3(16, IMG, 2), 256, 0, stream>>>(
            A2a, W2d + (size_t)(li * 2 + 0) * 147456, ff1_b + li * 128, nullptr, nullptr, A2v, nullptr);
        // cur = conv(A2v, ff2) + cur  (in-place, element-wise) + GN partial stats
        k_conv<false, false, true, true, false, true><<<dim3(16, IMG, 2), 256, 0, stream>>>(
            A2v, W2d + (size_t)(li * 2 + 1) * 147456, ff2_b + li * 128, cur, cur, nullptr, pstat);
        // GN apply: in-place on cur + A2a emit, or final NCHW transpose to d_out
        if (li == 4)
            k_gnapply<true><<<3072, 256, 0, stream>>>(cur, pstat, gn_w + li * 128,
                gn_b + li * 128, nullptr, nullptr, outp);
        else
            k_gnapply<false><<<3072, 256, 0, stream>>>(cur, pstat, gn_w + li * 128,
                gn_b + li * 128, cur, A2a, nullptr);
    }
}

// Round 10
// 684.381 us; speedup vs baseline: 1.0364x; 1.0364x over previous
//
#include <hip/hip_runtime.h>

// B=2, T=12, C=128, H=W=32, heads=4, dh=32, layers=5. fp32 I/O.
// Algebra: key-axis softmax cancels q-conv & att_b; attention weights are
// query-independent (head output broadcast over the 12 frames).
// Layout: channels-last fp32 activations [img][1024px][128c] + padded bf16
// copies A2[img][34*34 pos][128c] so conv MFMA A-fragments are direct
// contiguous global loads (no LDS in the convs).
// R10 (=R8 resubmit): per-tap batched loads double-buffered one tap ahead,
// sched_barrier(0) between load-batch and MFMA-batch so the compiler cannot
// sink the loads (R7's rotation was optimized away: VGPR_Count=32).
#define NELEM 3145728
#define IMG 24
#define CH 128
#define HW 1024
#define PADP 1156          // 34*34
#define A2IMG 147968       // 1156*128

using short8  = __attribute__((ext_vector_type(8))) short;
using float4v = __attribute__((ext_vector_type(4))) float;

__device__ inline unsigned short f2bf(float f){
    union { float f; unsigned u; } c; c.f = f;
    return (unsigned short)((c.u + 0x7FFF + ((c.u >> 16) & 1)) >> 16);
}
__device__ inline float bf2f(unsigned short h){
    union { unsigned u; float f; } c; c.u = ((unsigned)h) << 16; return c.f;
}

// ---------------- weight transforms (fp32 -> bf16 MFMA-B layout) ----------------
__global__ void k_w2dense(const float* __restrict__ w1, const float* __restrict__ w2src,
                          unsigned short* __restrict__ dst){
    int idx = blockIdx.x * 256 + threadIdx.x;           // 10*147456
    if (idx >= 1474560) return;
    int li2 = idx / 147456, r1 = idx - li2 * 147456;
    int j = r1 & 7, t16 = r1 >> 3;
    int co = t16 & 127, tcq = t16 >> 7;
    int quad = tcq & 3, cc = (tcq >> 2) & 3, tap = tcq >> 4;
    const float* base = ((li2 & 1) ? w2src : w1) + (size_t)(li2 >> 1) * 147456;
    dst[idx] = f2bf(base[(co * 128 + cc * 32 + quad * 8 + j) * 9 + tap]);
}
__global__ void k_w2kv(const float* __restrict__ w, unsigned short* __restrict__ dst){
    int idx = blockIdx.x * 256 + threadIdx.x;           // 5*36864
    if (idx >= 184320) return;
    int li = idx / 36864, r1 = idx - li * 36864;
    int j = r1 & 7, t16 = r1 >> 3;
    int co = t16 & 127, tq = t16 >> 7;
    int quad = tq & 3, tap = tq >> 2;
    int h = co >> 5, col = co & 31;
    dst[idx] = f2bf(w[(size_t)(((li * 4 + h) * 32 + col) * 32 + quad * 8 + j) * 9 + tap]);
}

// ---------------- zero the padded borders of the A2 buffers ----------------
__global__ void k_border(unsigned short* __restrict__ a, unsigned short* __restrict__ b){
    int gid = blockIdx.x * 256 + threadIdx.x;   // 2*24*132*128 = 811008
    if (gid >= 811008) return;
    int c = gid & 127, r = gid >> 7;
    int bp = r % 132, r2 = r / 132;
    int img = r2 % 24, buf = r2 / 24;
    int pos;
    if (bp < 34) pos = bp;
    else if (bp < 68) pos = 33 * 34 + (bp - 34);
    else if (bp < 100) pos = (bp - 68 + 1) * 34;
    else pos = (bp - 100 + 1) * 34 + 33;
    unsigned short* p = buf ? b : a;
    p[(size_t)img * A2IMG + pos * 128 + c] = 0;
}

// ---------------- init: NCHW fp32 input -> CL cur fp32 + A2a bf16 ----------------
__global__ __launch_bounds__(256) void k_init(const float* __restrict__ in,
    float* __restrict__ cur, unsigned short* __restrict__ a2){
    int gid = blockIdx.x * 256 + threadIdx.x;   // 24*1024*32
    int c4 = (gid & 31) * 4, px = (gid >> 5) & 1023, img = gid >> 15;
    float4v v;
    #pragma unroll
    for (int j = 0; j < 4; j++)
        v[j] = in[((size_t)img * 128 + c4 + j) * HW + px];
    *(float4v*)(cur + ((size_t)img * HW + px) * 128 + c4) = v;
    int pos = ((px >> 5) + 1) * 34 + (px & 31) + 1;
    unsigned short* ap = a2 + ((size_t)img * PADP + pos) * 128 + c4;
    #pragma unroll
    for (int j = 0; j < 4; j++) ap[j] = f2bf(v[j]);
}

// ---------------- implicit-GEMM 3x3 conv, channels-last, no LDS ----------------
// grid (16 rq, 24 img, 2 zc) = 768 blocks (3/CU -> 3 waves/SIMD). 4 waves/block.
// Wave: row y0+wm (32 px, 2 m-frags) x 32 co (2 n-frags).
// Dense: per tap, batch 8 A + 8 B loads -> 16 MFMAs; ping-pong double-buffered
// one tap ahead, sched_barrier(0) fencing load-batch from MFMA-batch.
// Grouped (K=9, 4 loads/tap): 3-slot rotation, consume-then-reload same slot.
template<bool GROUPED, bool RELU, bool RES, bool EF32, bool EA2, bool STAT>
__global__ __launch_bounds__(256, 3) void k_conv(
    const unsigned short* __restrict__ a2in, const unsigned short* __restrict__ w2,
    const float* __restrict__ bias, const float* __restrict__ res,
    float* __restrict__ outf, unsigned short* __restrict__ outa2,
    float* __restrict__ pstat)
{
    const int y0 = blockIdx.x * 2;
    const int img = blockIdx.y;
    const int zc = blockIdx.z;
    const int t = threadIdx.x;
    const int wave = t >> 6, lane = t & 63;
    const int wm = wave & 1, wn = wave >> 1;
    const int n16 = lane & 15, quad = lane >> 4;
    const int cog = zc * 64 + wn * 32;          // wave's co base
    const int head = zc * 2 + wn;               // co group (grouped head / GN group)
    const int y = y0 + wm;                      // wave's image row

    constexpr int NCC = GROUPED ? 1 : 4;

    const short8* w8 = reinterpret_cast<const short8*>(w2);
    // abase folds in the lane's channel offset (quad*8) and, for grouped, head*32.
    const unsigned short* abase = a2in + (size_t)img * A2IMG
                                + (GROUPED ? head * 32 : 0) + quad * 8;

    float4v acc[2][2];
    #pragma unroll
    for (int a = 0; a < 2; a++)
        #pragma unroll
        for (int b = 0; b < 2; b++) acc[a][b] = (float4v){0.f,0.f,0.f,0.f};

    auto loadTap = [&](int tap, short8 (&A)[NCC][2], short8 (&B)[NCC][2]){
        const int ky = tap / 3, kx = tap - ky * 3;
        #pragma unroll
        for (int cc = 0; cc < NCC; cc++) {
            #pragma unroll
            for (int mt = 0; mt < 2; mt++) {
                int pos = (y + ky) * 34 + mt * 16 + kx + n16;
                A[cc][mt] = *reinterpret_cast<const short8*>(
                    abase + (size_t)pos * 128 + cc * 32);
            }
            const int k = GROUPED ? tap : tap * 4 + cc;
            #pragma unroll
            for (int nt = 0; nt < 2; nt++)
                B[cc][nt] = w8[(k * 4 + quad) * 128 + cog + nt * 16 + n16];
        }
    };
    auto mfmaTap = [&](short8 (&A)[NCC][2], short8 (&B)[NCC][2]){
        #pragma unroll
        for (int cc = 0; cc < NCC; cc++)
            #pragma unroll
            for (int mt = 0; mt < 2; mt++)
                #pragma unroll
                for (int nt = 0; nt < 2; nt++)
                    acc[mt][nt] = __builtin_amdgcn_mfma_f32_16x16x32_bf16(
                        A[cc][mt], B[cc][nt], acc[mt][nt], 0, 0, 0);
    };

    if (!GROUPED) {
        // ping-pong: load tap k+1 into the idle buffer while consuming tap k.
        short8 A0[NCC][2], B0[NCC][2], A1[NCC][2], B1[NCC][2];
        loadTap(0, A0, B0);
        #pragma unroll
        for (int tap = 0; tap < 9; tap++) {
            if ((tap & 1) == 0) {
                if (tap < 8) loadTap(tap + 1, A1, B1);
                __builtin_amdgcn_sched_barrier(0);   // loads stay above MFMAs
                mfmaTap(A0, B0);
            } else {
                if (tap < 8) loadTap(tap + 1, A0, B0);
                __builtin_amdgcn_sched_barrier(0);
                mfmaTap(A1, B1);
            }
        }
    } else {
        // 3-slot rotation: consume slot, then reload it for tap+3 (no hazard).
        short8 A0[NCC][2], B0[NCC][2], A1[NCC][2], B1[NCC][2], A2s[NCC][2], B2s[NCC][2];
        loadTap(0, A0, B0);
        loadTap(1, A1, B1);
        loadTap(2, A2s, B2s);
        #pragma unroll
        for (int tap = 0; tap < 9; tap++) {
            const int ph = tap % 3;
            if (ph == 0) {
                mfmaTap(A0, B0);
                __builtin_amdgcn_sched_barrier(0);
                if (tap < 6) loadTap(tap + 3, A0, B0);
            } else if (ph == 1) {
                mfmaTap(A1, B1);
                __builtin_amdgcn_sched_barrier(0);
                if (tap < 6) loadTap(tap + 3, A1, B1);
            } else {
                mfmaTap(A2s, B2s);
                __builtin_amdgcn_sched_barrier(0);
                if (tap < 6) loadTap(tap + 3, A2s, B2s);
            }
        }
    }

    // epilogue: D col = n16 (co offset), row = quad*4+reg (x offset)
    float s1 = 0.f, s2 = 0.f;
    #pragma unroll
    for (int mt = 0; mt < 2; mt++) {
        int xb = mt * 16 + quad * 4;
        #pragma unroll
        for (int nt = 0; nt < 2; nt++) {
            int co = cog + nt * 16 + n16;
            float bb = bias[co];
            #pragma unroll
            for (int r = 0; r < 4; r++) {
                int px = y * 32 + xb + r;
                float val = acc[mt][nt][r] + bb;
                if (RELU) val = fmaxf(val, 0.f);
                size_t ci = ((size_t)img * HW + px) * 128 + co;
                if (RES) val += res[ci];
                if (EF32) outf[ci] = val;
                if (EA2) {
                    int pos = (y + 1) * 34 + xb + r + 1;
                    outa2[((size_t)img * PADP + pos) * 128 + co] = f2bf(val);
                }
                if (STAT) { s1 += val; s2 += val * val; }
            }
        }
    }
    if (STAT) {
        #pragma unroll
        for (int o = 32; o > 0; o >>= 1) {
            s1 += __shfl_down(s1, o); s2 += __shfl_down(s2, o);
        }
        if (lane == 0) {
            atomicAdd(&pstat[(img * 4 + head) * 2], s1);
            atomicAdd(&pstat[(img * 4 + head) * 2 + 1], s2);
        }
    }
}

// ---------------- attention logit conv (reads padded bf16 A2v) ----------------
__global__ __launch_bounds__(256) void k_attn(
    const unsigned short* __restrict__ a2v, const float* __restrict__ aw,
    float* __restrict__ ak, float* __restrict__ pstat)
{
    const int img = blockIdx.x;            // b*12 + l
    const int h = blockIdx.y;
    const int y0 = blockIdx.z * 8;
    const int t = threadIdx.x;
    const int b = img / 12, l = img - b * 12;

    if (blockIdx.x == 0 && blockIdx.y == 0 && blockIdx.z == 0 && t < 192)
        pstat[t] = 0.f;                     // zero GN stats for this layer's ff2

    __shared__ float sxv[32 * 341];         // ci-major, pos stride 341
    __shared__ float spos[32];
    if (t < 32) {
        int j2 = t & ~1;
        float freq = __expf(-(float)j2 * 0.28782313662425576f);
        float ang = (float)l * freq;
        spos[t] = (t & 1) ? __cosf(ang) : __sinf(ang);
    }
    __syncthreads();

    // stage 10 padded rows x 34 cols x 32 ci, add pos on interior
    const unsigned short* vb = a2v + (size_t)img * A2IMG + h * 32;
    for (int idx = t; idx < 1360; idx += 256) {
        int q = idx & 3, pos = idx >> 2;
        int ppos = y0 * 34 + pos;
        int row = y0 + pos / 34, col = pos - (pos / 34) * 34;
        bool inter = (row >= 1 && row <= 32 && col >= 1 && col <= 32);
        short8 vv = *reinterpret_cast<const short8*>(vb + (size_t)ppos * 128 + q * 8);
        #pragma unroll
        for (int j = 0; j < 8; j++) {
            float f = bf2f((unsigned short)vv[j]);
            if (inter) f += spos[q * 8 + j];
            sxv[(q * 8 + j) * 341 + pos] = f;
        }
    }
    __syncthreads();

    const float* wb = aw + (h * 64 + 32) * 9;   // K-half weights (uniform -> s_load)
    const int r = t >> 5, xx = t & 31;
    float acc = 0.f;
    #pragma unroll 4
    for (int ci = 0; ci < 32; ci++) {
        #pragma unroll
        for (int ky = 0; ky < 3; ky++)
            #pragma unroll
            for (int kx = 0; kx < 3; kx++)
                acc = fmaf(sxv[ci * 341 + (r + ky) * 34 + xx + kx],
                           wb[ci * 9 + ky * 3 + kx], acc);
    }
    ak[((b * 4 + h) * 12 + l) * HW + (y0 + r) * 32 + xx] = acc;
}

// ---------------- fused softmax + weighted sum + residual (+A2a emit) ----------------
__global__ __launch_bounds__(256) void k_wsum(const float* __restrict__ ak,
    const float* __restrict__ v, float* __restrict__ cur,
    unsigned short* __restrict__ a2a)
{
    int gid = blockIdx.x * 256 + threadIdx.x;   // 2*1024*32
    int c4 = (gid & 31) * 4, px = (gid >> 5) & 1023, b = gid >> 15;
    int h = c4 >> 5;
    const float* wp = ak + ((b * 4 + h) * 12) * HW + px;
    float a[12], m = -1e30f;
    #pragma unroll
    for (int l = 0; l < 12; l++) { a[l] = wp[l * HW]; m = fmaxf(m, a[l]); }
    float ssum = 0.f;
    #pragma unroll
    for (int l = 0; l < 12; l++) { a[l] = __expf(a[l] - m); ssum += a[l]; }
    float invs = 1.f / ssum;
    float4v s = (float4v){0.f,0.f,0.f,0.f};
    #pragma unroll
    for (int l = 0; l < 12; l++) {
        float4v vv = *(const float4v*)(v + (((size_t)(b * 12 + l) * HW) + px) * 128 + c4);
        #pragma unroll
        for (int j = 0; j < 4; j++) s[j] += a[l] * vv[j];
    }
    #pragma unroll
    for (int j = 0; j < 4; j++) s[j] *= invs;
    int pos = ((px >> 5) + 1) * 34 + (px & 31) + 1;
    #pragma unroll
    for (int l = 0; l < 12; l++) {
        size_t ci = (((size_t)(b * 12 + l) * HW) + px) * 128 + c4;
        float4v cv = *(float4v*)(cur + ci);
        #pragma unroll
        for (int j = 0; j < 4; j++) cv[j] += s[j];
        *(float4v*)(cur + ci) = cv;
        unsigned short* ap = a2a + ((size_t)(b * 12 + l) * PADP + pos) * 128 + c4;
        #pragma unroll
        for (int j = 0; j < 4; j++) ap[j] = f2bf(cv[j]);
    }
}

// ---------------- GroupNorm finalize+apply (in-place on cur / final NCHW) ----------------
template<bool LAST>
__global__ __launch_bounds__(256) void k_gnapply(const float* __restrict__ y,
    const float* __restrict__ pstat, const float* __restrict__ gw,
    const float* __restrict__ gb, float* __restrict__ cur,
    unsigned short* __restrict__ a2a, float* __restrict__ outp)
{
    int gid = blockIdx.x * 256 + threadIdx.x;   // 24*1024*32
    if (!LAST) {
        int c4 = (gid & 31) * 4, px = (gid >> 5) & 1023, img = gid >> 15;
        int g = c4 >> 5;
        float S = pstat[(img * 4 + g) * 2], Q = pstat[(img * 4 + g) * 2 + 1];
        float mu = S * (1.f / 32768.f);
        float inv = rsqrtf(Q * (1.f / 32768.f) - mu * mu + 1e-5f);
        float4v vv = *(const float4v*)(y + ((size_t)img * HW + px) * 128 + c4);
        int pos = ((px >> 5) + 1) * 34 + (px & 31) + 1;
        size_t ci = ((size_t)img * HW + px) * 128 + c4;
        unsigned short* ap = a2a + ((size_t)img * PADP + pos) * 128 + c4;
        #pragma unroll
        for (int j = 0; j < 4; j++) {
            float val = (vv[j] - mu) * inv * gw[c4 + j] + gb[c4 + j];
            vv[j] = val;
            ap[j] = f2bf(val);
        }
        *(float4v*)(cur + ci) = vv;
    } else {
        int px4 = (gid & 255) * 4, c = (gid >> 8) & 127, img = gid >> 15;
        int g = c >> 5;
        float S = pstat[(img * 4 + g) * 2], Q = pstat[(img * 4 + g) * 2 + 1];
        float mu = S * (1.f / 32768.f);
        float inv = rsqrtf(Q * (1.f / 32768.f) - mu * mu + 1e-5f);
        float gg = gw[c], bb = gb[c];
        float4v o;
        #pragma unroll
        for (int j = 0; j < 4; j++) {
            float val = y[((size_t)img * HW + px4 + j) * 128 + c];
            o[j] = (val - mu) * inv * gg + bb;
        }
        *(float4v*)(outp + ((size_t)img * 128 + c) * HW + px4) = o;
    }
}

extern "C" void kernel_launch(void* const* d_in, const int* in_sizes, int n_in,
                              void* d_out, int out_size, void* d_ws, size_t ws_size,
                              hipStream_t stream)
{
    const float* input = (const float*)d_in[0];
    // d_in[1] q_w, d_in[2] q_b, d_in[6] att_b cancel in key-axis softmax.
    const float* kv_w  = (const float*)d_in[3];
    const float* kv_b  = (const float*)d_in[4];
    const float* att_w = (const float*)d_in[5];
    const float* ff1_w = (const float*)d_in[7];
    const float* ff1_b = (const float*)d_in[8];
    const float* ff2_w = (const float*)d_in[9];
    const float* ff2_b = (const float*)d_in[10];
    const float* gn_w  = (const float*)d_in[11];
    const float* gn_b  = (const float*)d_in[12];

    // ws layout (~30.5 MB): no buffer aliases another live buffer.
    float* ws  = (float*)d_ws;
    float* cur = ws;                          // CL fp32 (24,1024,128)
    float* ak  = ws + (size_t)NELEM;          // 98304
    float* pstat = ak + 98304;                // 192
    unsigned short* W2d  = (unsigned short*)(pstat + 192);   // 1,474,560
    unsigned short* W2kv = W2d + 1474560;                    // 184,320
    unsigned short* A2v  = W2kv + 184320;                    // 24*147968
    unsigned short* A2a  = A2v + (size_t)IMG * A2IMG;        // 24*147968
    // d_out doubles as the fp32 v buffer (dead before the final output write).
    float* v    = (float*)d_out;
    float* outp = (float*)d_out;

    k_w2dense<<<5760, 256, 0, stream>>>(ff1_w, ff2_w, W2d);
    k_w2kv<<<720, 256, 0, stream>>>(kv_w, W2kv);
    k_border<<<3168, 256, 0, stream>>>(A2a, A2v);
    k_init<<<3072, 256, 0, stream>>>(input, cur, A2a);

    for (int li = 0; li < 5; li++) {
        // v (d_out) = grouped conv(A2a) + kv_b ; also emit A2v bf16
        k_conv<true, false, false, true, true, false><<<dim3(16, IMG, 2), 256, 0, stream>>>(
            A2a, W2kv + (size_t)li * 36864, kv_b + li * 128, nullptr, v, A2v, nullptr);
        // attention logits from k = v + pos (also zeroes pstat for this layer)
        k_attn<<<dim3(IMG, 4, 4), 256, 0, stream>>>(A2v, att_w + (size_t)li * 2304, ak, pstat);
        // cur += softmax-weighted sum of v (broadcast over frames); emit A2a
        k_wsum<<<256, 256, 0, stream>>>(ak, v, cur, A2a);
        // f1 = relu(conv(A2a, ff1)) -> A2v only
        k_conv<false, true, false, false, true, false><<<dim3(16, IMG, 2), 256, 0, stream>>>(
            A2a, W2d + (size_t)(li * 2 + 0) * 147456, ff1_b + li * 128, nullptr, nullptr, A2v, nullptr);
        // cur = conv(A2v, ff2) + cur  (in-place, element-wise) + GN partial stats
        k_conv<false, false, true, true, false, true><<<dim3(16, IMG, 2), 256, 0, stream>>>(
            A2v, W2d + (size_t)(li * 2 + 1) * 147456, ff2_b + li * 128, cur, cur, nullptr, pstat);
        // GN apply: in-place on cur + A2a emit, or final NCHW transpose to d_out
        if (li == 4)
            k_gnapply<true><<<3072, 256, 0, stream>>>(cur, pstat, gn_w + li * 128,
                gn_b + li * 128, nullptr, nullptr, outp);
        else
            k_gnapply<false><<<3072, 256, 0, stream>>>(cur, pstat, gn_w + li * 128,
                gn_b + li * 128, cur, A2a, nullptr);
    }
}